// Round 1
// baseline (481.763 us; speedup 1.0000x reference)
//
#include <hip/hip_runtime.h>
#include <math.h>

// Problem constants (match reference)
#define DIM 16777216
#define TAU 0.01f
#define CONSISTENCY_WEIGHT 0.1f
#define SATURATION 5.0f
#define FAST_RATE 0.01f
#define SLOW_RATE 0.001f
#define FAST_DECAY 0.9995f
#define SCHEMA_SPEEDUP 15.0f

constexpr int BLOCK = 256;
constexpr int NBLOCKS = 4096;          // 4096*256 = 1,048,576 threads; DIM/4 = 4,194,304 float4s -> 4 iters/thread
constexpr int WAVES_PER_BLOCK = BLOCK / 64;

// Kernel 1: fused elementwise (new_narrative, velocity) + partial reductions
// of sum(deviation^2) and sum(css^2). One partial pair per block into ws.
__global__ __launch_bounds__(BLOCK) void ni_main_kernel(
    const float* __restrict__ summary,   // (4, DIM)
    const float* __restrict__ narrative, // (DIM,)
    const float* __restrict__ tonic,     // (DIM,)
    float* __restrict__ out,             // [0,DIM)=new_narrative [DIM,2DIM)=velocity
    float* __restrict__ partials)        // ws: [0,NBLOCKS)=dev2, [NBLOCKS,2*NBLOCKS)=css2
{
    const float4* a0 = (const float4*)(summary);
    const float4* a1 = (const float4*)(summary + (size_t)DIM);
    const float4* a2 = (const float4*)(summary + (size_t)2 * DIM);
    const float4* a3 = (const float4*)(summary + (size_t)3 * DIM);
    const float4* n4 = (const float4*)narrative;
    const float4* t4 = (const float4*)tonic;
    float4* newn = (float4*)out;
    float4* vel  = (float4*)(out + (size_t)DIM);

    float sum_dev = 0.0f;
    float sum_css = 0.0f;

    const int n = DIM / 4;
    for (int i = blockIdx.x * BLOCK + threadIdx.x; i < n; i += NBLOCKS * BLOCK) {
        float4 v0 = a0[i];
        float4 v1 = a1[i];
        float4 v2 = a2[i];
        float4 v3 = a3[i];
        float4 nn = n4[i];
        float4 tt = t4[i];

        float4 css;
        css.x = 0.25f * (v0.x + v1.x + v2.x + v3.x);
        css.y = 0.25f * (v0.y + v1.y + v2.y + v3.y);
        css.z = 0.25f * (v0.z + v1.z + v2.z + v3.z);
        css.w = 0.25f * (v0.w + v1.w + v2.w + v3.w);

        float4 dv;
        dv.x = css.x - nn.x;
        dv.y = css.y - nn.y;
        dv.z = css.z - nn.z;
        dv.w = css.w - nn.w;

        float4 nw;
        nw.x = nn.x * (1.0f - TAU) + css.x * TAU + tt.x;
        nw.y = nn.y * (1.0f - TAU) + css.y * TAU + tt.y;
        nw.z = nn.z * (1.0f - TAU) + css.z * TAU + tt.z;
        nw.w = nn.w * (1.0f - TAU) + css.w * TAU + tt.w;

        float4 ve;
        ve.x = nw.x - nn.x;
        ve.y = nw.y - nn.y;
        ve.z = nw.z - nn.z;
        ve.w = nw.w - nn.w;

        sum_dev += dv.x * dv.x + dv.y * dv.y + dv.z * dv.z + dv.w * dv.w;
        sum_css += css.x * css.x + css.y * css.y + css.z * css.z + css.w * css.w;

        newn[i] = nw;
        vel[i]  = ve;
    }

    // wave(64) shuffle reduce
    #pragma unroll
    for (int off = 32; off > 0; off >>= 1) {
        sum_dev += __shfl_down(sum_dev, off, 64);
        sum_css += __shfl_down(sum_css, off, 64);
    }

    __shared__ float sdev[WAVES_PER_BLOCK];
    __shared__ float scss[WAVES_PER_BLOCK];
    const int lane = threadIdx.x & 63;
    const int wave = threadIdx.x >> 6;
    if (lane == 0) {
        sdev[wave] = sum_dev;
        scss[wave] = sum_css;
    }
    __syncthreads();
    if (threadIdx.x == 0) {
        float d = 0.0f, c = 0.0f;
        #pragma unroll
        for (int w = 0; w < WAVES_PER_BLOCK; ++w) {
            d += sdev[w];
            c += scss[w];
        }
        partials[blockIdx.x] = d;                 // written unconditionally -> poison-safe
        partials[NBLOCKS + blockIdx.x] = c;
    }
}

// Kernel 2: reduce NBLOCKS partials, compute the three scalar outputs.
__global__ __launch_bounds__(1024) void ni_finalize_kernel(
    const float* __restrict__ partials,
    const float* __restrict__ fast_p,
    const float* __restrict__ slow_p,
    float* __restrict__ out)
{
    float sd = 0.0f, sc = 0.0f;
    for (int i = threadIdx.x; i < NBLOCKS; i += 1024) {
        sd += partials[i];
        sc += partials[NBLOCKS + i];
    }
    #pragma unroll
    for (int off = 32; off > 0; off >>= 1) {
        sd += __shfl_down(sd, off, 64);
        sc += __shfl_down(sc, off, 64);
    }
    __shared__ float s1[16];
    __shared__ float s2[16];
    const int lane = threadIdx.x & 63;
    const int wave = threadIdx.x >> 6;
    if (lane == 0) {
        s1[wave] = sd;
        s2[wave] = sc;
    }
    __syncthreads();
    if (threadIdx.x == 0) {
        float d = 0.0f, c = 0.0f;
        #pragma unroll
        for (int w = 0; w < 16; ++w) {
            d += s1[w];
            c += s2[w];
        }
        const float dev_norm = sqrtf(d);
        const float css_norm = sqrtf(c);
        const float consistency_loss = CONSISTENCY_WEIGHT * dev_norm;

        const float fast = *fast_p;
        const float slow = *slow_p;

        const float input_gate = fminf(1.0f, css_norm);
        const float delta_fast = FAST_RATE / (1.0f + fast * SATURATION) * input_gate;
        const float fast_new = fminf(fast * FAST_DECAY + delta_fast, 0.7f);

        const float schema_fit = fminf(fmaxf(1.0f - dev_norm, 0.0f), 1.0f);
        const float schema_multiplier = 1.0f + SCHEMA_SPEEDUP * schema_fit * schema_fit;
        const float delta_slow = SLOW_RATE / (1.0f + slow * SATURATION) * schema_multiplier;
        const float slow_new = fminf(slow + delta_slow, 1.0f);

        const float identity_strength = fminf(fast_new + slow_new, 1.0f);

        out[(size_t)2 * DIM + 0] = consistency_loss;
        out[(size_t)2 * DIM + 1] = identity_strength;
        out[(size_t)2 * DIM + 2] = dev_norm;
    }
}

extern "C" void kernel_launch(void* const* d_in, const int* in_sizes, int n_in,
                              void* d_out, int out_size, void* d_ws, size_t ws_size,
                              hipStream_t stream) {
    const float* summary   = (const float*)d_in[0];  // (4, DIM)
    const float* narrative = (const float*)d_in[1];  // (DIM,)
    const float* tonic     = (const float*)d_in[2];  // (DIM,)
    const float* fast_p    = (const float*)d_in[3];  // scalar
    const float* slow_p    = (const float*)d_in[4];  // scalar
    float* out = (float*)d_out;
    float* partials = (float*)d_ws;                  // needs 2*NBLOCKS*4 = 32 KB

    ni_main_kernel<<<NBLOCKS, BLOCK, 0, stream>>>(summary, narrative, tonic, out, partials);
    ni_finalize_kernel<<<1, 1024, 0, stream>>>(partials, fast_p, slow_p, out);
}

// Round 2
// 466.525 us; speedup vs baseline: 1.0327x; 1.0327x over previous
//
#include <hip/hip_runtime.h>
#include <math.h>

// Problem constants (match reference)
#define DIM 16777216
#define TAU 0.01f
#define CONSISTENCY_WEIGHT 0.1f
#define SATURATION 5.0f
#define FAST_RATE 0.01f
#define SLOW_RATE 0.001f
#define FAST_DECAY 0.9995f
#define SCHEMA_SPEEDUP 15.0f

constexpr int BLOCK = 256;
constexpr int NBLOCKS = 4096;
constexpr int STRIDE = NBLOCKS * BLOCK;            // 1,048,576 threads
constexpr int ITERS = (DIM / 4) / STRIDE;          // 4 float4s per thread per stream (compile-time)
constexpr int WAVES_PER_BLOCK = BLOCK / 64;

typedef float f4 __attribute__((ext_vector_type(4)));

// Kernel 1: fused elementwise (new_narrative, velocity) + partial reductions
// of sum(deviation^2) and sum(css^2). One partial pair per block into ws.
// All global traffic is pure streaming (no reuse) -> nontemporal hints.
__global__ __launch_bounds__(BLOCK) void ni_main_kernel(
    const float* __restrict__ summary,   // (4, DIM)
    const float* __restrict__ narrative, // (DIM,)
    const float* __restrict__ tonic,     // (DIM,)
    float* __restrict__ out,             // [0,DIM)=new_narrative [DIM,2DIM)=velocity
    float* __restrict__ partials)        // ws: [0,NBLOCKS)=dev2, [NBLOCKS,2*NBLOCKS)=css2
{
    const f4* a0 = (const f4*)(summary);
    const f4* a1 = (const f4*)(summary + (size_t)DIM);
    const f4* a2 = (const f4*)(summary + (size_t)2 * DIM);
    const f4* a3 = (const f4*)(summary + (size_t)3 * DIM);
    const f4* n4 = (const f4*)narrative;
    const f4* t4 = (const f4*)tonic;
    f4* newn = (f4*)out;
    f4* vel  = (f4*)(out + (size_t)DIM);

    f4 sum_dev4 = {0.0f, 0.0f, 0.0f, 0.0f};
    f4 sum_css4 = {0.0f, 0.0f, 0.0f, 0.0f};

    const int i0 = blockIdx.x * BLOCK + threadIdx.x;

    #pragma unroll
    for (int k = 0; k < ITERS; ++k) {
        const int i = i0 + k * STRIDE;

        f4 v0 = __builtin_nontemporal_load(a0 + i);
        f4 v1 = __builtin_nontemporal_load(a1 + i);
        f4 v2 = __builtin_nontemporal_load(a2 + i);
        f4 v3 = __builtin_nontemporal_load(a3 + i);
        f4 nn = __builtin_nontemporal_load(n4 + i);
        f4 tt = __builtin_nontemporal_load(t4 + i);

        f4 css = 0.25f * ((v0 + v1) + (v2 + v3));
        f4 dv  = css - nn;
        f4 nw  = nn * (1.0f - TAU) + css * TAU + tt;
        f4 ve  = nw - nn;

        sum_dev4 += dv * dv;
        sum_css4 += css * css;

        __builtin_nontemporal_store(nw, newn + i);
        __builtin_nontemporal_store(ve, vel + i);
    }

    float sum_dev = (sum_dev4.x + sum_dev4.y) + (sum_dev4.z + sum_dev4.w);
    float sum_css = (sum_css4.x + sum_css4.y) + (sum_css4.z + sum_css4.w);

    // wave(64) shuffle reduce
    #pragma unroll
    for (int off = 32; off > 0; off >>= 1) {
        sum_dev += __shfl_down(sum_dev, off, 64);
        sum_css += __shfl_down(sum_css, off, 64);
    }

    __shared__ float sdev[WAVES_PER_BLOCK];
    __shared__ float scss[WAVES_PER_BLOCK];
    const int lane = threadIdx.x & 63;
    const int wave = threadIdx.x >> 6;
    if (lane == 0) {
        sdev[wave] = sum_dev;
        scss[wave] = sum_css;
    }
    __syncthreads();
    if (threadIdx.x == 0) {
        float d = 0.0f, c = 0.0f;
        #pragma unroll
        for (int w = 0; w < WAVES_PER_BLOCK; ++w) {
            d += sdev[w];
            c += scss[w];
        }
        partials[blockIdx.x] = d;                 // written unconditionally -> poison-safe
        partials[NBLOCKS + blockIdx.x] = c;
    }
}

// Kernel 2: reduce NBLOCKS partials, compute the three scalar outputs.
__global__ __launch_bounds__(1024) void ni_finalize_kernel(
    const float* __restrict__ partials,
    const float* __restrict__ fast_p,
    const float* __restrict__ slow_p,
    float* __restrict__ out)
{
    float sd = 0.0f, sc = 0.0f;
    for (int i = threadIdx.x; i < NBLOCKS; i += 1024) {
        sd += partials[i];
        sc += partials[NBLOCKS + i];
    }
    #pragma unroll
    for (int off = 32; off > 0; off >>= 1) {
        sd += __shfl_down(sd, off, 64);
        sc += __shfl_down(sc, off, 64);
    }
    __shared__ float s1[16];
    __shared__ float s2[16];
    const int lane = threadIdx.x & 63;
    const int wave = threadIdx.x >> 6;
    if (lane == 0) {
        s1[wave] = sd;
        s2[wave] = sc;
    }
    __syncthreads();
    if (threadIdx.x == 0) {
        float d = 0.0f, c = 0.0f;
        #pragma unroll
        for (int w = 0; w < 16; ++w) {
            d += s1[w];
            c += s2[w];
        }
        const float dev_norm = sqrtf(d);
        const float css_norm = sqrtf(c);
        const float consistency_loss = CONSISTENCY_WEIGHT * dev_norm;

        const float fast = *fast_p;
        const float slow = *slow_p;

        const float input_gate = fminf(1.0f, css_norm);
        const float delta_fast = FAST_RATE / (1.0f + fast * SATURATION) * input_gate;
        const float fast_new = fminf(fast * FAST_DECAY + delta_fast, 0.7f);

        const float schema_fit = fminf(fmaxf(1.0f - dev_norm, 0.0f), 1.0f);
        const float schema_multiplier = 1.0f + SCHEMA_SPEEDUP * schema_fit * schema_fit;
        const float delta_slow = SLOW_RATE / (1.0f + slow * SATURATION) * schema_multiplier;
        const float slow_new = fminf(slow + delta_slow, 1.0f);

        const float identity_strength = fminf(fast_new + slow_new, 1.0f);

        out[(size_t)2 * DIM + 0] = consistency_loss;
        out[(size_t)2 * DIM + 1] = identity_strength;
        out[(size_t)2 * DIM + 2] = dev_norm;
    }
}

extern "C" void kernel_launch(void* const* d_in, const int* in_sizes, int n_in,
                              void* d_out, int out_size, void* d_ws, size_t ws_size,
                              hipStream_t stream) {
    const float* summary   = (const float*)d_in[0];  // (4, DIM)
    const float* narrative = (const float*)d_in[1];  // (DIM,)
    const float* tonic     = (const float*)d_in[2];  // (DIM,)
    const float* fast_p    = (const float*)d_in[3];  // scalar
    const float* slow_p    = (const float*)d_in[4];  // scalar
    float* out = (float*)d_out;
    float* partials = (float*)d_ws;                  // needs 2*NBLOCKS*4 = 32 KB

    ni_main_kernel<<<NBLOCKS, BLOCK, 0, stream>>>(summary, narrative, tonic, out, partials);
    ni_finalize_kernel<<<1, 1024, 0, stream>>>(partials, fast_p, slow_p, out);
}